// Round 12
// baseline (394.286 us; speedup 1.0000x reference)
//
#include <hip/hip_runtime.h>
#include <hip/hip_bf16.h>
#include <hip/hip_fp16.h>

static constexpr int HN = 32;     // Hemb == Hgcn == 32
static constexpr int NIN = 128;
static constexpr int CH1 = 8192;  // edges per phase-1 block
static constexpr int CAP2 = 12288; // LDS stage capacity (ints) in phase 2
// sqrt(log2(e)): folded into packed fp16 h so the score dot is in exp2 domain.
static constexpr float SQRT_LOG2E = 1.2011224087864498f;

typedef _Float16 h2v __attribute__((ext_vector_type(2)));

__device__ __forceinline__ float bf2f(unsigned short u) {
    union { unsigned int i; float f; } v;
    v.i = ((unsigned int)u) << 16;
    return v.f;
}
__device__ __forceinline__ float ldf(const void* p, size_t i, int isbf) {
    return isbf ? bf2f(((const unsigned short*)p)[i]) : ((const float*)p)[i];
}
__device__ __forceinline__ unsigned int pack2h(float a, float b) {
    unsigned short ua = __half_as_ushort(__float2half_rn(a));
    unsigned short ub = __half_as_ushort(__float2half_rn(b));
    return (unsigned int)ua | ((unsigned int)ub << 16);
}
__device__ __forceinline__ float2 up2(unsigned int u) {
    __half2 h2;
    *reinterpret_cast<unsigned int*>(&h2) = u;
    return __half22float2(h2);
}
__device__ __forceinline__ float2 upbf2(unsigned int u) {
    float2 r;
    r.x = bf2f((unsigned short)(u & 0xFFFFu));
    r.y = bf2f((unsigned short)(u >> 16));
    return r;
}
// packed-fp16 2-way dot-accumulate (v_dot2_f32_f16), f32 accumulator.
__device__ __forceinline__ float fd2(unsigned int a, unsigned int b, float c) {
#if __has_builtin(__builtin_amdgcn_fdot2)
    return __builtin_amdgcn_fdot2(__builtin_bit_cast(h2v, a),
                                  __builtin_bit_cast(h2v, b), c, false);
#else
    float2 fa = up2(a), fb = up2(b);
    return c + fa.x * fb.x + fa.y * fb.y;
#endif
}
// order-preserving float->uint map for atomicMax-based global max
__device__ __forceinline__ unsigned int fmap(float f) {
    unsigned int u = __float_as_uint(f);
    return (f >= 0.f) ? (u | 0x80000000u) : ~u;
}
__device__ __forceinline__ float funmap(unsigned int u) {
    return (u & 0x80000000u) ? __uint_as_float(u & 0x7FFFFFFFu)
                             : __uint_as_float(~u);
}

// K1: h = relu(x @ Wemb + bemb) -> fp32. Shuffle-fed GEMM: x never staged
// in LDS (registers + __shfl broadcast); only We (paired float2) + bias in
// LDS (16.4KB -> ~8 blocks/CU vs old 33KB/2.6 blocks; old version was
// latency-bound at 32% occupancy, 51us for a ~6us-floor kernel).
__global__ __launch_bounds__(256) void embed1_kernel(
    const void* __restrict__ x,
    const void* __restrict__ Wemb,
    const void* __restrict__ bemb,
    const int* __restrict__ flagp,
    float* __restrict__ h, int N)
{
    __shared__ float2 Ws2[64 * 32];   // Ws2[kk*32+f] = (We[2kk][f], We[2kk+1][f])
    __shared__ float be[HN];
    const int tid = threadIdx.x;
    const int isbf = flagp[0];

    for (int i = tid; i < NIN * HN; i += 256) {
        int k = i >> 5, f = i & 31;
        float v = ldf(Wemb, i, isbf);
        ((float*)Ws2)[(((k >> 1) * 32 + f) << 1) | (k & 1)] = v;
    }
    if (tid < HN) be[tid] = ldf(bemb, tid, isbf);
    __syncthreads();

    const int f = tid & 31;           // feature lane
    const int s = tid >> 5;           // node slot 0..7
    const int n0 = blockIdx.x * 64;

    #pragma unroll
    for (int it = 0; it < 4; ++it) {
        int na = n0 + it * 16 + s;
        int nb = na + 8;
        int nac = (na < N) ? na : 0;  // clamped load index
        int nbc = (nb < N) ? nb : 0;
        float acca = be[f], accb = be[f];
        if (isbf) {
            const unsigned int* x2 = (const unsigned int*)x;
            unsigned int a0 = x2[(size_t)nac * 64 + f];
            unsigned int a1 = x2[(size_t)nac * 64 + 32 + f];
            unsigned int b0 = x2[(size_t)nbc * 64 + f];
            unsigned int b1 = x2[(size_t)nbc * 64 + 32 + f];
            #pragma unroll
            for (int kk = 0; kk < 32; ++kk) {
                float2 w2 = Ws2[(kk << 5) | f];
                float2 va = upbf2(__shfl(a0, kk, 32));
                float2 vb = upbf2(__shfl(b0, kk, 32));
                acca += va.x * w2.x + va.y * w2.y;
                accb += vb.x * w2.x + vb.y * w2.y;
            }
            #pragma unroll
            for (int kk = 0; kk < 32; ++kk) {
                float2 w2 = Ws2[((kk + 32) << 5) | f];
                float2 va = upbf2(__shfl(a1, kk, 32));
                float2 vb = upbf2(__shfl(b1, kk, 32));
                acca += va.x * w2.x + va.y * w2.y;
                accb += vb.x * w2.x + vb.y * w2.y;
            }
        } else {
            const float2* x2 = (const float2*)x;
            float2 a0 = x2[(size_t)nac * 64 + f];
            float2 a1 = x2[(size_t)nac * 64 + 32 + f];
            float2 b0 = x2[(size_t)nbc * 64 + f];
            float2 b1 = x2[(size_t)nbc * 64 + 32 + f];
            #pragma unroll
            for (int kk = 0; kk < 32; ++kk) {
                float2 w2 = Ws2[(kk << 5) | f];
                float2 va, vb;
                va.x = __shfl(a0.x, kk, 32); va.y = __shfl(a0.y, kk, 32);
                vb.x = __shfl(b0.x, kk, 32); vb.y = __shfl(b0.y, kk, 32);
                acca += va.x * w2.x + va.y * w2.y;
                accb += vb.x * w2.x + vb.y * w2.y;
            }
            #pragma unroll
            for (int kk = 0; kk < 32; ++kk) {
                float2 w2 = Ws2[((kk + 32) << 5) | f];
                float2 va, vb;
                va.x = __shfl(a1.x, kk, 32); va.y = __shfl(a1.y, kk, 32);
                vb.x = __shfl(b1.x, kk, 32); vb.y = __shfl(b1.y, kk, 32);
                acca += va.x * w2.x + va.y * w2.y;
                accb += vb.x * w2.x + vb.y * w2.y;
            }
        }
        if (na < N) h[(size_t)na * HN + f] = fmaxf(acca, 0.f);
        if (nb < N) h[(size_t)nb * HN + f] = fmaxf(accb, 0.f);
    }
}

// K2: coarse bucket histogram (bucket = col>>8), LDS-aggregated; stores
// per-block histogram to blkhist for phase1 reuse. Block 0 lanes 0-63 run
// the bf16-vs-fp32 input sniff.
__global__ __launch_bounds__(512) void bhist_kernel(
    const int* __restrict__ col, int* __restrict__ bucket_cnt, int E, int B,
    int* __restrict__ blkhist,
    const unsigned int* __restrict__ xw, int* __restrict__ flag)
{
    __shared__ int hist[512];
    const int t = threadIdx.x;
    const int e0 = blockIdx.x * CH1;
    for (int i = t; i < B; i += 512) hist[i] = 0;
    if (blockIdx.x == 0 && t < 64) {
        int hits = 0;
        #pragma unroll
        for (int k = 0; k < 2; ++k) {
            unsigned int w = xw[t + 64 * k];
            float a = bf2f((unsigned short)(w & 0xFFFFu));
            float aa = fabsf(a);
            if (a == 0.0f || (aa >= 0.000244140625f && aa <= 32.0f)) hits++;
        }
        #pragma unroll
        for (int m = 32; m; m >>= 1) hits += __shfl_xor(hits, m, 64);
        if (t == 0) flag[0] = (hits >= 64) ? 1 : 0;
    }
    __syncthreads();
    #pragma unroll
    for (int k = 0; k < CH1 / 512; ++k) {
        int e = e0 + k * 512 + t;
        if (e < E) atomicAdd(&hist[col[e] >> 8], 1);
    }
    __syncthreads();
    for (int i = t; i < B; i += 512) {
        int v = hist[i];
        blkhist[(size_t)blockIdx.x * B + i] = v;
        if (v) atomicAdd(&bucket_cnt[i], v);
    }
}

// K3: exclusive scan of bucket counts (B <= 512); init cursors; rowptr[N]=E.
__global__ __launch_bounds__(512) void bscan_kernel(
    const int* __restrict__ bucket_cnt, int* __restrict__ bucket_base,
    int* __restrict__ bucket_cursor, int* __restrict__ rowptr,
    int B, int N, int E)
{
    __shared__ int sc[512];
    __shared__ int orig[512];
    const int t = threadIdx.x;
    int v0 = (t < B) ? bucket_cnt[t] : 0;
    sc[t] = v0; orig[t] = v0;
    __syncthreads();
    for (int o = 1; o < 512; o <<= 1) {
        int v = (t >= o) ? sc[t - o] : 0;
        __syncthreads();
        sc[t] += v;
        __syncthreads();
    }
    if (t < B) {
        int ex = sc[t] - orig[t];
        bucket_base[t] = ex;
        bucket_cursor[t] = ex;
    }
    if (t == 0) { bucket_base[B] = E; rowptr[N] = E; }
}

// K4 (phase1): bucketize edges with LDS reorder -> semi-coalesced writes of
// packed words (row<<8 | col&255) grouped by bucket. bucket = col>>8.
// Histogram comes precomputed from bhist via blkhist (single col pass here).
__global__ __launch_bounds__(512) void phase1_kernel(
    const int* __restrict__ row, const int* __restrict__ col,
    const int* __restrict__ blkhist,
    int* __restrict__ bucket_cursor, int* __restrict__ bucketed, int E, int B)
{
    __shared__ int hist[512];
    __shared__ int sc[512];
    __shared__ int cnt[512];
    __shared__ int gbase[512];
    __shared__ int word[CH1];
    __shared__ int dst[CH1];
    const int t = threadIdx.x;
    const int e0 = blockIdx.x * CH1;
    const int M = (E - e0 < CH1) ? (E - e0) : CH1;

    for (int i = t; i < B; i += 512) {
        hist[i] = blkhist[(size_t)blockIdx.x * B + i];
        cnt[i] = 0;
    }
    __syncthreads();
    sc[t] = (t < B) ? hist[t] : 0;
    __syncthreads();
    for (int o = 1; o < 512; o <<= 1) {
        int v = (t >= o) ? sc[t - o] : 0;
        __syncthreads();
        sc[t] += v;
        __syncthreads();
    }
    if (t < B && hist[t])
        gbase[t] = atomicAdd(&bucket_cursor[t], hist[t]);
    __syncthreads();
    #pragma unroll
    for (int k = 0; k < CH1 / 512; ++k) {
        int e = e0 + k * 512 + t;
        if (e < E) {
            int c = col[e], r = row[e];
            int b = c >> 8;
            int lr = atomicAdd(&cnt[b], 1);
            int p = sc[b] - hist[b] + lr;     // exclusive scan + rank
            word[p] = (r << 8) | (c & 255);
            dst[p] = gbase[b] + lr;
        }
    }
    __syncthreads();
    for (int i = t; i < M; i += 512)
        bucketed[dst[i]] = word[i];
}

// K5 (phase2): one block per bucket. Pass 1 counts per-node degrees AND
// saves each edge's per-node rank (rank_s, u16); scan -> rowptr; pass 2
// pure-arithmetic placement into LDS stage; coalesced copy-out.
__global__ __launch_bounds__(256) void phase2_kernel(
    const int* __restrict__ bucketed, const int* __restrict__ bucket_base,
    int* __restrict__ rowptr, int* __restrict__ csr_src, int N)
{
    __shared__ int stage[CAP2];
    __shared__ unsigned short rank_s[CAP2];
    __shared__ int cnt[256];
    __shared__ int sc[256];
    __shared__ int loc[256];
    const int t = threadIdx.x, b = blockIdx.x;
    const int node0 = b << 8;
    const int s0 = bucket_base[b], s1 = bucket_base[b + 1];
    const int segsz = s1 - s0;
    cnt[t] = 0;
    __syncthreads();
    for (int i = s0 + t; i < s1; i += 256) {
        int lc = bucketed[i] & 255;
        int r = atomicAdd(&cnt[lc], 1);
        if (i - s0 < CAP2) rank_s[i - s0] = (unsigned short)r;
    }
    __syncthreads();
    int c = cnt[t];
    sc[t] = c;
    __syncthreads();
    for (int o = 1; o < 256; o <<= 1) {
        int v = (t >= o) ? sc[t - o] : 0;
        __syncthreads();
        sc[t] += v;
        __syncthreads();
    }
    int ex = sc[t] - c;                 // local exclusive offset
    loc[t] = ex;
    if (node0 + t < N) rowptr[node0 + t] = s0 + ex;
    cnt[t] = 0;                         // placement cursor (fallback path only)
    __syncthreads();
    if (segsz <= CAP2) {
        for (int i = s0 + t; i < s1; i += 256) {
            int w = bucketed[i];
            stage[loc[w & 255] + rank_s[i - s0]] = w >> 8;
        }
        __syncthreads();
        for (int i = t; i < segsz; i += 256) csr_src[s0 + i] = stage[i];
    } else {
        for (int i = s0 + t; i < s1; i += 256) {
            int w = bucketed[i];
            int lc = w & 255;
            int off = loc[lc] + atomicAdd(&cnt[lc], 1);
            csr_src[s0 + off] = w >> 8;
        }
    }
}

// K8: packed[v] = one 128B line per node: 8 chunks of {h[4j..4j+3] fp16
// (pre-scaled by sqrt(log2e)), hws[4j..4j+3] fp16} with hws = dis*(h@Wgcn).
__global__ __launch_bounds__(256) void embed2_kernel(
    const float* __restrict__ h, const void* __restrict__ Wgcn,
    const int* __restrict__ rowptr, const int* __restrict__ flagp,
    uint4* __restrict__ packed, int N)
{
    __shared__ float Wg[HN * HN];
    __shared__ float hs[32][HN + 1];
    __shared__ float ws[32][HN + 1];
    const int tid = threadIdx.x;
    const int isbf = flagp[0];
    for (int i = tid; i < HN * HN; i += 256) Wg[i] = ldf(Wgcn, i, isbf);
    const int n0 = blockIdx.x * 32;
    for (int i = tid; i < 32 * HN; i += 256) {
        int n = i >> 5, f = i & 31;
        hs[n][f] = (n0 + n < N) ? h[(size_t)(n0 + n) * HN + f] : 0.f;
    }
    __syncthreads();
    const int f = tid & 31, ns = tid >> 5;
    #pragma unroll
    for (int g = 0; g < 4; ++g) {
        int n = ns + 8 * g, v = n0 + n;
        float acc = 0.f;
        #pragma unroll
        for (int k = 0; k < HN; ++k) acc += hs[n][k] * Wg[k * HN + f];
        float dis = (v < N) ? rsqrtf((float)(rowptr[v + 1] - rowptr[v]) + 1.0f) : 0.f;
        ws[n][f] = dis * acc;
    }
    __syncthreads();
    const int n = tid >> 3, jj = tid & 7, v = n0 + n;
    if (v < N) {
        uint4 w;
        w.x = pack2h(hs[n][4 * jj + 0] * SQRT_LOG2E, hs[n][4 * jj + 1] * SQRT_LOG2E);
        w.y = pack2h(hs[n][4 * jj + 2] * SQRT_LOG2E, hs[n][4 * jj + 3] * SQRT_LOG2E);
        w.z = pack2h(ws[n][4 * jj + 0], ws[n][4 * jj + 1]);
        w.w = pack2h(ws[n][4 * jj + 2], ws[n][4 * jj + 3]);
        packed[(size_t)v * 8 + jj] = w;
    }
}

// K9 (passB): fused gather pass, online softmax (exp2 domain), fdot2 scores.
// 4-deep edge unroll. Single dispatch (round-11 3-way split was -15us of
// tail/launch overhead; instrumentation served its purpose, reverted).
__global__ __launch_bounds__(256) void passB_kernel(
    const float* __restrict__ h, const uint4* __restrict__ packed,
    const int* __restrict__ csr_src, const int* __restrict__ rowptr,
    const void* __restrict__ t, const void* __restrict__ bgcn,
    const int* __restrict__ flagp,
    float* __restrict__ outr, float* __restrict__ outz,
    float* __restrict__ out0_ml, float* __restrict__ denout, int N)
{
    const int tid = threadIdx.x;
    const int lane = tid & 31;
    const int sub = lane >> 3;
    const int j = lane & 7;
    const int v = blockIdx.x * 8 + (tid >> 5);
    if (v >= N) return;
    const int isbf = flagp[0];

    const float4* h4 = (const float4*)h;
    float4 hv = h4[(size_t)v * 8 + j];          // fp32 self (rep path)
    uint4 sw = packed[(size_t)v * 8 + j];       // self line: scaled h + hws
    float2 wsv0 = up2(sw.z), wsv1 = up2(sw.w);
    const int s = rowptr[v], e2 = rowptr[v + 1];

    float m = -1e30f, den = 0.f, num = 0.f;     // m in log2 domain
    float ax = 0.f, ay = 0.f, az = 0.f, aw = 0.f;
    int i = s + sub;
    for (; i + 12 < e2; i += 16) {
        int r0 = csr_src[i];
        int r1 = csr_src[i + 4];
        int r2 = csr_src[i + 8];
        int r3 = csr_src[i + 12];
        uint4 w0 = packed[(size_t)r0 * 8 + j];
        uint4 w1 = packed[(size_t)r1 * 8 + j];
        uint4 w2 = packed[(size_t)r2 * 8 + j];
        uint4 w3 = packed[(size_t)r3 * 8 + j];
        float tr0 = ldf(t, r0, isbf);
        float tr1 = ldf(t, r1, isbf);
        float tr2 = ldf(t, r2, isbf);
        float tr3 = ldf(t, r3, isbf);
        float p0 = fd2(w0.x, sw.x, fd2(w0.y, sw.y, 0.f));
        float p1 = fd2(w1.x, sw.x, fd2(w1.y, sw.y, 0.f));
        float p2 = fd2(w2.x, sw.x, fd2(w2.y, sw.y, 0.f));
        float p3 = fd2(w3.x, sw.x, fd2(w3.y, sw.y, 0.f));
        p0 += __shfl_xor(p0, 1, 32);
        p0 += __shfl_xor(p0, 2, 32);
        p0 += __shfl_xor(p0, 4, 32);
        p1 += __shfl_xor(p1, 1, 32);
        p1 += __shfl_xor(p1, 2, 32);
        p1 += __shfl_xor(p1, 4, 32);
        p2 += __shfl_xor(p2, 1, 32);
        p2 += __shfl_xor(p2, 2, 32);
        p2 += __shfl_xor(p2, 4, 32);
        p3 += __shfl_xor(p3, 1, 32);
        p3 += __shfl_xor(p3, 2, 32);
        p3 += __shfl_xor(p3, 4, 32);
        float2 a00 = up2(w0.z), a01 = up2(w0.w);
        float2 a10 = up2(w1.z), a11 = up2(w1.w);
        float2 a20 = up2(w2.z), a21 = up2(w2.w);
        float2 a30 = up2(w3.z), a31 = up2(w3.w);
        ax += (a00.x + a10.x) + (a20.x + a30.x);
        ay += (a00.y + a10.y) + (a20.y + a30.y);
        az += (a01.x + a11.x) + (a21.x + a31.x);
        aw += (a01.y + a11.y) + (a21.y + a31.y);
        float mn = fmaxf(m, fmaxf(fmaxf(p0, p1), fmaxf(p2, p3)));
        float corr = exp2f(m - mn);
        float e0 = exp2f(p0 - mn), e1 = exp2f(p1 - mn);
        float e2x = exp2f(p2 - mn), e3 = exp2f(p3 - mn);
        den = den * corr + (e0 + e1) + (e2x + e3);
        num = num * corr + (e0 * tr0 + e1 * tr1) + (e2x * tr2 + e3 * tr3);
        m = mn;
    }
    for (; i + 4 < e2; i += 8) {
        int r0 = csr_src[i];
        int r1 = csr_src[i + 4];
        uint4 w0 = packed[(size_t)r0 * 8 + j];
        uint4 w1 = packed[(size_t)r1 * 8 + j];
        float tr0 = ldf(t, r0, isbf);
        float tr1 = ldf(t, r1, isbf);
        float p0 = fd2(w0.x, sw.x, fd2(w0.y, sw.y, 0.f));
        float p1 = fd2(w1.x, sw.x, fd2(w1.y, sw.y, 0.f));
        p0 += __shfl_xor(p0, 1, 32);
        p0 += __shfl_xor(p0, 2, 32);
        p0 += __shfl_xor(p0, 4, 32);
        p1 += __shfl_xor(p1, 1, 32);
        p1 += __shfl_xor(p1, 2, 32);
        p1 += __shfl_xor(p1, 4, 32);
        float2 a00 = up2(w0.z), a01 = up2(w0.w);
        float2 a10 = up2(w1.z), a11 = up2(w1.w);
        ax += a00.x + a10.x; ay += a00.y + a10.y;
        az += a01.x + a11.x; aw += a01.y + a11.y;
        float mn = fmaxf(m, fmaxf(p0, p1));
        float corr = exp2f(m - mn);
        float e0 = exp2f(p0 - mn), e1 = exp2f(p1 - mn);
        den = den * corr + e0 + e1;
        num = num * corr + e0 * tr0 + e1 * tr1;
        m = mn;
    }
    if (i < e2) {
        int r0 = csr_src[i];
        uint4 w0 = packed[(size_t)r0 * 8 + j];
        float tr0 = ldf(t, r0, isbf);
        float p0 = fd2(w0.x, sw.x, fd2(w0.y, sw.y, 0.f));
        p0 += __shfl_xor(p0, 1, 32);
        p0 += __shfl_xor(p0, 2, 32);
        p0 += __shfl_xor(p0, 4, 32);
        float2 a00 = up2(w0.z), a01 = up2(w0.w);
        ax += a00.x; ay += a00.y; az += a01.x; aw += a01.y;
        float mn = fmaxf(m, p0);
        float corr = exp2f(m - mn);
        float e0 = exp2f(p0 - mn);
        den = den * corr + e0;
        num = num * corr + e0 * tr0;
        m = mn;
    }
    #pragma unroll
    for (int o = 8; o <= 16; o <<= 1) {
        float mo = __shfl_xor(m, o, 32);
        float dno = __shfl_xor(den, o, 32);
        float nmo = __shfl_xor(num, o, 32);
        float mn = fmaxf(m, mo);
        float ca = exp2f(m - mn), cb = exp2f(mo - mn);
        den = den * ca + dno * cb;
        num = num * ca + nmo * cb;
        m = mn;
        ax += __shfl_xor(ax, o, 32);
        ay += __shfl_xor(ay, o, 32);
        az += __shfl_xor(az, o, 32);
        aw += __shfl_xor(aw, o, 32);
    }

    float dv = rsqrtf((float)(e2 - s) + 1.0f);
    float4 rep;
    rep.x = hv.x + fmaxf(dv * (ax + wsv0.x) + ldf(bgcn, 4 * j + 0, isbf), 0.f);
    rep.y = hv.y + fmaxf(dv * (ay + wsv0.y) + ldf(bgcn, 4 * j + 1, isbf), 0.f);
    rep.z = hv.z + fmaxf(dv * (az + wsv1.x) + ldf(bgcn, 4 * j + 2, isbf), 0.f);
    rep.w = hv.w + fmaxf(dv * (aw + wsv1.y) + ldf(bgcn, 4 * j + 3, isbf), 0.f);
    if (sub == 0)
        ((float4*)outr)[(size_t)v * 8 + j] = rep;
    if (lane == 0) {
        outz[v]    = num / fmaxf(den, 1e-37f);
        out0_ml[v] = m;          // log2 domain
        denout[v]  = den;
    }
}

// K10: global max over per-node local maxes -> single global atomicMax
// (order-preserving uint mapping; amax_u pre-zeroed = -inf).
__global__ __launch_bounds__(256) void amax1_kernel(
    const float* __restrict__ ml, unsigned int* __restrict__ amax_u, int N)
{
    float m = -INFINITY;
    for (int i = blockIdx.x * 256 + threadIdx.x; i < N; i += 256 * 256)
        m = fmaxf(m, ml[i]);
    #pragma unroll
    for (int s = 32; s; s >>= 1) m = fmaxf(m, __shfl_xor(m, s, 64));
    __shared__ float sm[4];
    if ((threadIdx.x & 63) == 0) sm[threadIdx.x >> 6] = m;
    __syncthreads();
    if (threadIdx.x == 0) {
        float bm = fmaxf(fmaxf(sm[0], sm[1]), fmaxf(sm[2], sm[3]));
        atomicMax(amax_u, fmap(bm));
    }
}

// K11: exact epsilon correction (log2 domain) + FF head.
__global__ __launch_bounds__(256) void final_kernel(
    const float* __restrict__ rep_in,
    const void* __restrict__ t, const int* __restrict__ flagp,
    const unsigned int* __restrict__ amax_u, const float* __restrict__ denarr,
    const void* __restrict__ W1, const void* __restrict__ b1,
    const void* __restrict__ W2, const void* __restrict__ b2,
    float* __restrict__ out0, float* __restrict__ outz, int N)
{
    __shared__ float W1s[34 * HN];
    __shared__ float b1s[HN], W2s[HN];
    __shared__ float b2s;
    const int tid = threadIdx.x;
    const int isbf = flagp[0];
    for (int i = tid; i < 34 * HN; i += 256) W1s[i] = ldf(W1, i, isbf);
    if (tid < HN) {
        b1s[tid] = ldf(b1, tid, isbf);
        W2s[tid] = ldf(W2, tid, isbf);
    }
    if (tid == 0) b2s = ldf(b2, 0, isbf);
    __syncthreads();

    const int lane = tid & 31;
    const int v = blockIdx.x * 8 + (tid >> 5);
    if (v >= N) return;

    float rep = rep_in[(size_t)v * HN + lane];
    float ml  = out0[v];
    float den = denarr[v];
    float zh  = outz[v];
    float am  = funmap(amax_u[0]);
    float term = (1e-8f / den) * exp2f(am - ml);   // log2-domain stabilizer
    float z = zh / (1.0f + term);
    float tv = ldf(t, v, isbf);

    float acc = b1s[lane] + tv * W1s[32 * HN + lane] + z * W1s[33 * HN + lane];
    #pragma unroll
    for (int k = 0; k < HN; ++k)
        acc += __shfl(rep, k, 32) * W1s[k * HN + lane];
    float f1 = fmaxf(acc, 0.f);
    float o = f1 * W2s[lane];
    #pragma unroll
    for (int m = 16; m; m >>= 1) o += __shfl_xor(o, m, 32);

    if (lane == 0) {
        out0[v] = o + b2s;
        outz[v] = z;
    }
}

extern "C" void kernel_launch(void* const* d_in, const int* in_sizes, int n_in,
                              void* d_out, int out_size, void* d_ws, size_t ws_size,
                              hipStream_t stream)
{
    const int N = out_size / 34;   // out[N] + rep[N*32] + z[N]
    const int E = in_sizes[2];

    const void* x    = d_in[0];
    const void* t    = d_in[1];
    const int* row   = (const int*)d_in[2];
    const int* col   = (const int*)d_in[3];
    const void* Wemb = d_in[4];
    const void* bemb = d_in[5];
    const void* Wgcn = d_in[6];
    const void* bgcn = d_in[7];
    const void* W1   = d_in[8];
    const void* b1   = d_in[9];
    const void* W2   = d_in[10];
    const void* b2   = d_in[11];

    const int B   = (N + 255) >> 8;         // coarse buckets (<=512 for N<=131072)
    const int NB1 = (E + CH1 - 1) / CH1;    // phase1/bhist blocks

    // ws: h | hwbuf(bucketed->packed) | csr_src | rowptr | den
    //     | bucket_cnt+amax_u (one memset) | bucket_base | bucket_cursor | flag
    char* wsb = (char*)d_ws;
    size_t off = 0;
    float* h        = (float*)(wsb + off); off += (size_t)N * HN * 4;
    size_t hwbytes  = (size_t)N * HN * 4;  // == N*128B packed line region
    if ((size_t)E * 4 > hwbytes) hwbytes = (size_t)E * 4;
    char*  hwreg    = wsb + off;           off += hwbytes;
    int*   csr_src  = (int*)(wsb + off);   off += (size_t)E * 4;
    int*   rowptr   = (int*)(wsb + off);   off += (size_t)(N + 1) * 4;
    float* den      = (float*)(wsb + off); off += (size_t)N * 4;
    int*   bucket_cnt    = (int*)(wsb + off); off += (size_t)B * 4;
    unsigned int* amax_u = (unsigned int*)(wsb + off); off += 4;
    int*   bucket_base   = (int*)(wsb + off); off += (size_t)(B + 1) * 4;
    int*   bucket_cursor = (int*)(wsb + off); off += (size_t)B * 4;
    int*   flag     = (int*)(wsb + off);   off += 4;

    int*   bucketed = (int*)hwreg;         // phase 1..2
    uint4* packed   = (uint4*)hwreg;       // after phase2: N x 128B fp16 lines
    // blkhist parks in the csr_src region (dead until phase2 overwrites it).
    int*   blkhist  = csr_src;

    // zero bucket_cnt AND amax_u (adjacent) in one memset
    hipMemsetAsync(bucket_cnt, 0, (size_t)(B + 1) * 4, stream);

    bhist_kernel<<<NB1, 512, 0, stream>>>(col, bucket_cnt, E, B, blkhist,
                                          (const unsigned int*)x, flag);
    embed1_kernel<<<(N + 63) / 64, 256, 0, stream>>>(x, Wemb, bemb, flag, h, N);
    bscan_kernel<<<1, 512, 0, stream>>>(bucket_cnt, bucket_base,
                                        bucket_cursor, rowptr, B, N, E);
    phase1_kernel<<<NB1, 512, 0, stream>>>(row, col, blkhist, bucket_cursor,
                                           bucketed, E, B);
    phase2_kernel<<<B, 256, 0, stream>>>(bucketed, bucket_base, rowptr,
                                         csr_src, N);
    embed2_kernel<<<(N + 31) / 32, 256, 0, stream>>>(h, Wgcn, rowptr, flag,
                                                     packed, N);

    float* outp = (float*)d_out;
    float* out0 = outp;
    float* outr = outp + N;
    float* outz = outp + (size_t)N * 33;

    passB_kernel<<<(N + 7) / 8, 256, 0, stream>>>(
        h, packed, csr_src, rowptr, t, bgcn, flag, outr, outz, out0, den, N);
    amax1_kernel<<<256, 256, 0, stream>>>(out0, amax_u, N);
    final_kernel<<<(N + 7) / 8, 256, 0, stream>>>(
        outr, t, flag, amax_u, den, W1, b1, W2, b2, out0, outz, N);
}

// Round 13
// 329.906 us; speedup vs baseline: 1.1951x; 1.1951x over previous
//
#include <hip/hip_runtime.h>
#include <hip/hip_bf16.h>
#include <hip/hip_fp16.h>

static constexpr int HN = 32;     // Hemb == Hgcn == 32
static constexpr int NIN = 128;
static constexpr int CH1 = 8192;  // edges per phase-1 block
static constexpr int CAP2 = 12288; // LDS stage capacity (ints) in phase 2
// sqrt(log2(e)): folded into packed fp16 h so the score dot is in exp2 domain.
static constexpr float SQRT_LOG2E = 1.2011224087864498f;

typedef _Float16 h2v __attribute__((ext_vector_type(2)));

__device__ __forceinline__ float bf2f(unsigned short u) {
    union { unsigned int i; float f; } v;
    v.i = ((unsigned int)u) << 16;
    return v.f;
}
__device__ __forceinline__ float ldf(const void* p, size_t i, int isbf) {
    return isbf ? bf2f(((const unsigned short*)p)[i]) : ((const float*)p)[i];
}
__device__ __forceinline__ unsigned int pack2h(float a, float b) {
    unsigned short ua = __half_as_ushort(__float2half_rn(a));
    unsigned short ub = __half_as_ushort(__float2half_rn(b));
    return (unsigned int)ua | ((unsigned int)ub << 16);
}
__device__ __forceinline__ float2 up2(unsigned int u) {
    __half2 h2;
    *reinterpret_cast<unsigned int*>(&h2) = u;
    return __half22float2(h2);
}
__device__ __forceinline__ float2 upbf2(unsigned int u) {
    float2 r;
    r.x = bf2f((unsigned short)(u & 0xFFFFu));
    r.y = bf2f((unsigned short)(u >> 16));
    return r;
}
// packed-fp16 2-way dot-accumulate (v_dot2_f32_f16), f32 accumulator.
__device__ __forceinline__ float fd2(unsigned int a, unsigned int b, float c) {
#if __has_builtin(__builtin_amdgcn_fdot2)
    return __builtin_amdgcn_fdot2(__builtin_bit_cast(h2v, a),
                                  __builtin_bit_cast(h2v, b), c, false);
#else
    float2 fa = up2(a), fb = up2(b);
    return c + fa.x * fb.x + fa.y * fb.y;
#endif
}
// order-preserving float->uint map for atomicMax-based global max
__device__ __forceinline__ unsigned int fmap(float f) {
    unsigned int u = __float_as_uint(f);
    return (f >= 0.f) ? (u | 0x80000000u) : ~u;
}
__device__ __forceinline__ float funmap(unsigned int u) {
    return (u & 0x80000000u) ? __uint_as_float(u & 0x7FFFFFFFu)
                             : __uint_as_float(~u);
}

// K1: h = relu(x @ Wemb + bemb) -> fp32. Round-9 structure (LDS-staged x,
// broadcast reads — NOT shuffle: __shfl is ds_bpermute on CDNA, strictly
// worse than same-address broadcast) with both operands packed fp16x2:
// LDS 33KB -> 16.4KB (residency 2.6 -> 8 blocks/CU) and LDS reads halved;
// inner op = v_dot2_f32_f16.
__global__ __launch_bounds__(256) void embed1_kernel(
    const void* __restrict__ x,
    const void* __restrict__ Wemb,
    const void* __restrict__ bemb,
    const int* __restrict__ flagp,
    float* __restrict__ h, int N)
{
    __shared__ unsigned int We2h[64 * 32]; // fp16x2 (We[2kk][f], We[2kk+1][f])
    __shared__ unsigned int xs2[32][64];   // fp16x2 (x[n][2kk], x[n][2kk+1])
    __shared__ float be[HN];
    const int tid = threadIdx.x;
    const int isbf = flagp[0];

    for (int i = tid; i < NIN * HN; i += 256) {
        int k = i >> 5, f = i & 31;
        float v = ldf(Wemb, i, isbf);
        ((unsigned short*)We2h)[((((k >> 1) << 5) | f) << 1) | (k & 1)] =
            __half_as_ushort(__float2half_rn(v));
    }
    if (tid < HN) be[tid] = ldf(bemb, tid, isbf);

    const int n0 = blockIdx.x * 32;
    if (isbf) {
        const unsigned int* xw = (const unsigned int*)x;   // bf16 pairs
        for (int i = tid; i < 32 * 64; i += 256) {
            int n = i >> 6, kk = i & 63;
            int nn = n0 + n;
            unsigned int u = (nn < N) ? xw[(size_t)nn * 64 + kk] : 0u;
            float2 v = upbf2(u);
            xs2[n][kk] = pack2h(v.x, v.y);
        }
    } else {
        const float2* x2 = (const float2*)x;
        for (int i = tid; i < 32 * 64; i += 256) {
            int n = i >> 6, kk = i & 63;
            int nn = n0 + n;
            float2 v;
            if (nn < N) v = x2[(size_t)nn * 64 + kk];
            else { v.x = 0.f; v.y = 0.f; }
            xs2[n][kk] = pack2h(v.x, v.y);
        }
    }
    __syncthreads();

    const int f = tid & 31, ns = tid >> 5;
    float a0 = be[f], a1 = be[f], a2 = be[f], a3 = be[f];
    #pragma unroll 8
    for (int kk = 0; kk < 64; ++kk) {
        unsigned int wv = We2h[(kk << 5) | f];   // lane f -> bank f, perfect
        a0 = fd2(xs2[ns +  0][kk], wv, a0);      // broadcast reads (free)
        a1 = fd2(xs2[ns +  8][kk], wv, a1);
        a2 = fd2(xs2[ns + 16][kk], wv, a2);
        a3 = fd2(xs2[ns + 24][kk], wv, a3);
    }
    if (n0 + ns      < N) h[(size_t)(n0 + ns     ) * HN + f] = fmaxf(a0, 0.f);
    if (n0 + ns +  8 < N) h[(size_t)(n0 + ns +  8) * HN + f] = fmaxf(a1, 0.f);
    if (n0 + ns + 16 < N) h[(size_t)(n0 + ns + 16) * HN + f] = fmaxf(a2, 0.f);
    if (n0 + ns + 24 < N) h[(size_t)(n0 + ns + 24) * HN + f] = fmaxf(a3, 0.f);
}

// K2: coarse bucket histogram (bucket = col>>8), LDS-aggregated; stores
// per-block histogram to blkhist for phase1 reuse. Block 0 lanes 0-63 run
// the bf16-vs-fp32 input sniff.
__global__ __launch_bounds__(512) void bhist_kernel(
    const int* __restrict__ col, int* __restrict__ bucket_cnt, int E, int B,
    int* __restrict__ blkhist,
    const unsigned int* __restrict__ xw, int* __restrict__ flag)
{
    __shared__ int hist[512];
    const int t = threadIdx.x;
    const int e0 = blockIdx.x * CH1;
    for (int i = t; i < B; i += 512) hist[i] = 0;
    if (blockIdx.x == 0 && t < 64) {
        int hits = 0;
        #pragma unroll
        for (int k = 0; k < 2; ++k) {
            unsigned int w = xw[t + 64 * k];
            float a = bf2f((unsigned short)(w & 0xFFFFu));
            float aa = fabsf(a);
            if (a == 0.0f || (aa >= 0.000244140625f && aa <= 32.0f)) hits++;
        }
        #pragma unroll
        for (int m = 32; m; m >>= 1) hits += __shfl_xor(hits, m, 64);
        if (t == 0) flag[0] = (hits >= 64) ? 1 : 0;
    }
    __syncthreads();
    #pragma unroll
    for (int k = 0; k < CH1 / 512; ++k) {
        int e = e0 + k * 512 + t;
        if (e < E) atomicAdd(&hist[col[e] >> 8], 1);
    }
    __syncthreads();
    for (int i = t; i < B; i += 512) {
        int v = hist[i];
        blkhist[(size_t)blockIdx.x * B + i] = v;
        if (v) atomicAdd(&bucket_cnt[i], v);
    }
}

// K3: exclusive scan of bucket counts (B <= 512); init cursors; rowptr[N]=E.
__global__ __launch_bounds__(512) void bscan_kernel(
    const int* __restrict__ bucket_cnt, int* __restrict__ bucket_base,
    int* __restrict__ bucket_cursor, int* __restrict__ rowptr,
    int B, int N, int E)
{
    __shared__ int sc[512];
    __shared__ int orig[512];
    const int t = threadIdx.x;
    int v0 = (t < B) ? bucket_cnt[t] : 0;
    sc[t] = v0; orig[t] = v0;
    __syncthreads();
    for (int o = 1; o < 512; o <<= 1) {
        int v = (t >= o) ? sc[t - o] : 0;
        __syncthreads();
        sc[t] += v;
        __syncthreads();
    }
    if (t < B) {
        int ex = sc[t] - orig[t];
        bucket_base[t] = ex;
        bucket_cursor[t] = ex;
    }
    if (t == 0) { bucket_base[B] = E; rowptr[N] = E; }
}

// K4 (phase1): bucketize edges with LDS reorder -> semi-coalesced writes of
// packed words (row<<8 | col&255) grouped by bucket. bucket = col>>8.
// Histogram comes precomputed from bhist via blkhist (single col pass here).
__global__ __launch_bounds__(512) void phase1_kernel(
    const int* __restrict__ row, const int* __restrict__ col,
    const int* __restrict__ blkhist,
    int* __restrict__ bucket_cursor, int* __restrict__ bucketed, int E, int B)
{
    __shared__ int hist[512];
    __shared__ int sc[512];
    __shared__ int cnt[512];
    __shared__ int gbase[512];
    __shared__ int word[CH1];
    __shared__ int dst[CH1];
    const int t = threadIdx.x;
    const int e0 = blockIdx.x * CH1;
    const int M = (E - e0 < CH1) ? (E - e0) : CH1;

    for (int i = t; i < B; i += 512) {
        hist[i] = blkhist[(size_t)blockIdx.x * B + i];
        cnt[i] = 0;
    }
    __syncthreads();
    sc[t] = (t < B) ? hist[t] : 0;
    __syncthreads();
    for (int o = 1; o < 512; o <<= 1) {
        int v = (t >= o) ? sc[t - o] : 0;
        __syncthreads();
        sc[t] += v;
        __syncthreads();
    }
    if (t < B && hist[t])
        gbase[t] = atomicAdd(&bucket_cursor[t], hist[t]);
    __syncthreads();
    #pragma unroll
    for (int k = 0; k < CH1 / 512; ++k) {
        int e = e0 + k * 512 + t;
        if (e < E) {
            int c = col[e], r = row[e];
            int b = c >> 8;
            int lr = atomicAdd(&cnt[b], 1);
            int p = sc[b] - hist[b] + lr;     // exclusive scan + rank
            word[p] = (r << 8) | (c & 255);
            dst[p] = gbase[b] + lr;
        }
    }
    __syncthreads();
    for (int i = t; i < M; i += 512)
        bucketed[dst[i]] = word[i];
}

// K5 (phase2): one block per bucket. Pass 1 counts per-node degrees AND
// saves each edge's per-node rank (rank_s, u16); scan -> rowptr; pass 2
// pure-arithmetic placement into LDS stage; coalesced copy-out.
__global__ __launch_bounds__(256) void phase2_kernel(
    const int* __restrict__ bucketed, const int* __restrict__ bucket_base,
    int* __restrict__ rowptr, int* __restrict__ csr_src, int N)
{
    __shared__ int stage[CAP2];
    __shared__ unsigned short rank_s[CAP2];
    __shared__ int cnt[256];
    __shared__ int sc[256];
    __shared__ int loc[256];
    const int t = threadIdx.x, b = blockIdx.x;
    const int node0 = b << 8;
    const int s0 = bucket_base[b], s1 = bucket_base[b + 1];
    const int segsz = s1 - s0;
    cnt[t] = 0;
    __syncthreads();
    for (int i = s0 + t; i < s1; i += 256) {
        int lc = bucketed[i] & 255;
        int r = atomicAdd(&cnt[lc], 1);
        if (i - s0 < CAP2) rank_s[i - s0] = (unsigned short)r;
    }
    __syncthreads();
    int c = cnt[t];
    sc[t] = c;
    __syncthreads();
    for (int o = 1; o < 256; o <<= 1) {
        int v = (t >= o) ? sc[t - o] : 0;
        __syncthreads();
        sc[t] += v;
        __syncthreads();
    }
    int ex = sc[t] - c;                 // local exclusive offset
    loc[t] = ex;
    if (node0 + t < N) rowptr[node0 + t] = s0 + ex;
    cnt[t] = 0;                         // placement cursor (fallback path only)
    __syncthreads();
    if (segsz <= CAP2) {
        for (int i = s0 + t; i < s1; i += 256) {
            int w = bucketed[i];
            stage[loc[w & 255] + rank_s[i - s0]] = w >> 8;
        }
        __syncthreads();
        for (int i = t; i < segsz; i += 256) csr_src[s0 + i] = stage[i];
    } else {
        for (int i = s0 + t; i < s1; i += 256) {
            int w = bucketed[i];
            int lc = w & 255;
            int off = loc[lc] + atomicAdd(&cnt[lc], 1);
            csr_src[s0 + off] = w >> 8;
        }
    }
}

// K8: packed[v] = one 128B line per node: 8 chunks of {h[4j..4j+3] fp16
// (pre-scaled by sqrt(log2e)), hws[4j..4j+3] fp16} with hws = dis*(h@Wgcn).
__global__ __launch_bounds__(256) void embed2_kernel(
    const float* __restrict__ h, const void* __restrict__ Wgcn,
    const int* __restrict__ rowptr, const int* __restrict__ flagp,
    uint4* __restrict__ packed, int N)
{
    __shared__ float Wg[HN * HN];
    __shared__ float hs[32][HN + 1];
    __shared__ float ws[32][HN + 1];
    const int tid = threadIdx.x;
    const int isbf = flagp[0];
    for (int i = tid; i < HN * HN; i += 256) Wg[i] = ldf(Wgcn, i, isbf);
    const int n0 = blockIdx.x * 32;
    for (int i = tid; i < 32 * HN; i += 256) {
        int n = i >> 5, f = i & 31;
        hs[n][f] = (n0 + n < N) ? h[(size_t)(n0 + n) * HN + f] : 0.f;
    }
    __syncthreads();
    const int f = tid & 31, ns = tid >> 5;
    #pragma unroll
    for (int g = 0; g < 4; ++g) {
        int n = ns + 8 * g, v = n0 + n;
        float acc = 0.f;
        #pragma unroll
        for (int k = 0; k < HN; ++k) acc += hs[n][k] * Wg[k * HN + f];
        float dis = (v < N) ? rsqrtf((float)(rowptr[v + 1] - rowptr[v]) + 1.0f) : 0.f;
        ws[n][f] = dis * acc;
    }
    __syncthreads();
    const int n = tid >> 3, jj = tid & 7, v = n0 + n;
    if (v < N) {
        uint4 w;
        w.x = pack2h(hs[n][4 * jj + 0] * SQRT_LOG2E, hs[n][4 * jj + 1] * SQRT_LOG2E);
        w.y = pack2h(hs[n][4 * jj + 2] * SQRT_LOG2E, hs[n][4 * jj + 3] * SQRT_LOG2E);
        w.z = pack2h(ws[n][4 * jj + 0], ws[n][4 * jj + 1]);
        w.w = pack2h(ws[n][4 * jj + 2], ws[n][4 * jj + 3]);
        packed[(size_t)v * 8 + jj] = w;
    }
}

// K9 (passB): fused gather pass, online softmax (exp2 domain), fdot2 scores.
// 4-deep edge unroll. Single dispatch.
__global__ __launch_bounds__(256) void passB_kernel(
    const float* __restrict__ h, const uint4* __restrict__ packed,
    const int* __restrict__ csr_src, const int* __restrict__ rowptr,
    const void* __restrict__ t, const void* __restrict__ bgcn,
    const int* __restrict__ flagp,
    float* __restrict__ outr, float* __restrict__ outz,
    float* __restrict__ out0_ml, float* __restrict__ denout, int N)
{
    const int tid = threadIdx.x;
    const int lane = tid & 31;
    const int sub = lane >> 3;
    const int j = lane & 7;
    const int v = blockIdx.x * 8 + (tid >> 5);
    if (v >= N) return;
    const int isbf = flagp[0];

    const float4* h4 = (const float4*)h;
    float4 hv = h4[(size_t)v * 8 + j];          // fp32 self (rep path)
    uint4 sw = packed[(size_t)v * 8 + j];       // self line: scaled h + hws
    float2 wsv0 = up2(sw.z), wsv1 = up2(sw.w);
    const int s = rowptr[v], e2 = rowptr[v + 1];

    float m = -1e30f, den = 0.f, num = 0.f;     // m in log2 domain
    float ax = 0.f, ay = 0.f, az = 0.f, aw = 0.f;
    int i = s + sub;
    for (; i + 12 < e2; i += 16) {
        int r0 = csr_src[i];
        int r1 = csr_src[i + 4];
        int r2 = csr_src[i + 8];
        int r3 = csr_src[i + 12];
        uint4 w0 = packed[(size_t)r0 * 8 + j];
        uint4 w1 = packed[(size_t)r1 * 8 + j];
        uint4 w2 = packed[(size_t)r2 * 8 + j];
        uint4 w3 = packed[(size_t)r3 * 8 + j];
        float tr0 = ldf(t, r0, isbf);
        float tr1 = ldf(t, r1, isbf);
        float tr2 = ldf(t, r2, isbf);
        float tr3 = ldf(t, r3, isbf);
        float p0 = fd2(w0.x, sw.x, fd2(w0.y, sw.y, 0.f));
        float p1 = fd2(w1.x, sw.x, fd2(w1.y, sw.y, 0.f));
        float p2 = fd2(w2.x, sw.x, fd2(w2.y, sw.y, 0.f));
        float p3 = fd2(w3.x, sw.x, fd2(w3.y, sw.y, 0.f));
        p0 += __shfl_xor(p0, 1, 32);
        p0 += __shfl_xor(p0, 2, 32);
        p0 += __shfl_xor(p0, 4, 32);
        p1 += __shfl_xor(p1, 1, 32);
        p1 += __shfl_xor(p1, 2, 32);
        p1 += __shfl_xor(p1, 4, 32);
        p2 += __shfl_xor(p2, 1, 32);
        p2 += __shfl_xor(p2, 2, 32);
        p2 += __shfl_xor(p2, 4, 32);
        p3 += __shfl_xor(p3, 1, 32);
        p3 += __shfl_xor(p3, 2, 32);
        p3 += __shfl_xor(p3, 4, 32);
        float2 a00 = up2(w0.z), a01 = up2(w0.w);
        float2 a10 = up2(w1.z), a11 = up2(w1.w);
        float2 a20 = up2(w2.z), a21 = up2(w2.w);
        float2 a30 = up2(w3.z), a31 = up2(w3.w);
        ax += (a00.x + a10.x) + (a20.x + a30.x);
        ay += (a00.y + a10.y) + (a20.y + a30.y);
        az += (a01.x + a11.x) + (a21.x + a31.x);
        aw += (a01.y + a11.y) + (a21.y + a31.y);
        float mn = fmaxf(m, fmaxf(fmaxf(p0, p1), fmaxf(p2, p3)));
        float corr = exp2f(m - mn);
        float e0 = exp2f(p0 - mn), e1 = exp2f(p1 - mn);
        float e2x = exp2f(p2 - mn), e3 = exp2f(p3 - mn);
        den = den * corr + (e0 + e1) + (e2x + e3);
        num = num * corr + (e0 * tr0 + e1 * tr1) + (e2x * tr2 + e3 * tr3);
        m = mn;
    }
    for (; i + 4 < e2; i += 8) {
        int r0 = csr_src[i];
        int r1 = csr_src[i + 4];
        uint4 w0 = packed[(size_t)r0 * 8 + j];
        uint4 w1 = packed[(size_t)r1 * 8 + j];
        float tr0 = ldf(t, r0, isbf);
        float tr1 = ldf(t, r1, isbf);
        float p0 = fd2(w0.x, sw.x, fd2(w0.y, sw.y, 0.f));
        float p1 = fd2(w1.x, sw.x, fd2(w1.y, sw.y, 0.f));
        p0 += __shfl_xor(p0, 1, 32);
        p0 += __shfl_xor(p0, 2, 32);
        p0 += __shfl_xor(p0, 4, 32);
        p1 += __shfl_xor(p1, 1, 32);
        p1 += __shfl_xor(p1, 2, 32);
        p1 += __shfl_xor(p1, 4, 32);
        float2 a00 = up2(w0.z), a01 = up2(w0.w);
        float2 a10 = up2(w1.z), a11 = up2(w1.w);
        ax += a00.x + a10.x; ay += a00.y + a10.y;
        az += a01.x + a11.x; aw += a01.y + a11.y;
        float mn = fmaxf(m, fmaxf(p0, p1));
        float corr = exp2f(m - mn);
        float e0 = exp2f(p0 - mn), e1 = exp2f(p1 - mn);
        den = den * corr + e0 + e1;
        num = num * corr + e0 * tr0 + e1 * tr1;
        m = mn;
    }
    if (i < e2) {
        int r0 = csr_src[i];
        uint4 w0 = packed[(size_t)r0 * 8 + j];
        float tr0 = ldf(t, r0, isbf);
        float p0 = fd2(w0.x, sw.x, fd2(w0.y, sw.y, 0.f));
        p0 += __shfl_xor(p0, 1, 32);
        p0 += __shfl_xor(p0, 2, 32);
        p0 += __shfl_xor(p0, 4, 32);
        float2 a00 = up2(w0.z), a01 = up2(w0.w);
        ax += a00.x; ay += a00.y; az += a01.x; aw += a01.y;
        float mn = fmaxf(m, p0);
        float corr = exp2f(m - mn);
        float e0 = exp2f(p0 - mn);
        den = den * corr + e0;
        num = num * corr + e0 * tr0;
        m = mn;
    }
    #pragma unroll
    for (int o = 8; o <= 16; o <<= 1) {
        float mo = __shfl_xor(m, o, 32);
        float dno = __shfl_xor(den, o, 32);
        float nmo = __shfl_xor(num, o, 32);
        float mn = fmaxf(m, mo);
        float ca = exp2f(m - mn), cb = exp2f(mo - mn);
        den = den * ca + dno * cb;
        num = num * ca + nmo * cb;
        m = mn;
        ax += __shfl_xor(ax, o, 32);
        ay += __shfl_xor(ay, o, 32);
        az += __shfl_xor(az, o, 32);
        aw += __shfl_xor(aw, o, 32);
    }

    float dv = rsqrtf((float)(e2 - s) + 1.0f);
    float4 rep;
    rep.x = hv.x + fmaxf(dv * (ax + wsv0.x) + ldf(bgcn, 4 * j + 0, isbf), 0.f);
    rep.y = hv.y + fmaxf(dv * (ay + wsv0.y) + ldf(bgcn, 4 * j + 1, isbf), 0.f);
    rep.z = hv.z + fmaxf(dv * (az + wsv1.x) + ldf(bgcn, 4 * j + 2, isbf), 0.f);
    rep.w = hv.w + fmaxf(dv * (aw + wsv1.y) + ldf(bgcn, 4 * j + 3, isbf), 0.f);
    if (sub == 0)
        ((float4*)outr)[(size_t)v * 8 + j] = rep;
    if (lane == 0) {
        outz[v]    = num / fmaxf(den, 1e-37f);
        out0_ml[v] = m;          // log2 domain
        denout[v]  = den;
    }
}

// K10: global max over per-node local maxes -> single global atomicMax
// (order-preserving uint mapping; amax_u pre-zeroed = -inf).
__global__ __launch_bounds__(256) void amax1_kernel(
    const float* __restrict__ ml, unsigned int* __restrict__ amax_u, int N)
{
    float m = -INFINITY;
    for (int i = blockIdx.x * 256 + threadIdx.x; i < N; i += 256 * 256)
        m = fmaxf(m, ml[i]);
    #pragma unroll
    for (int s = 32; s; s >>= 1) m = fmaxf(m, __shfl_xor(m, s, 64));
    __shared__ float sm[4];
    if ((threadIdx.x & 63) == 0) sm[threadIdx.x >> 6] = m;
    __syncthreads();
    if (threadIdx.x == 0) {
        float bm = fmaxf(fmaxf(sm[0], sm[1]), fmaxf(sm[2], sm[3]));
        atomicMax(amax_u, fmap(bm));
    }
}

// K11: exact epsilon correction (log2 domain) + FF head.
__global__ __launch_bounds__(256) void final_kernel(
    const float* __restrict__ rep_in,
    const void* __restrict__ t, const int* __restrict__ flagp,
    const unsigned int* __restrict__ amax_u, const float* __restrict__ denarr,
    const void* __restrict__ W1, const void* __restrict__ b1,
    const void* __restrict__ W2, const void* __restrict__ b2,
    float* __restrict__ out0, float* __restrict__ outz, int N)
{
    __shared__ float W1s[34 * HN];
    __shared__ float b1s[HN], W2s[HN];
    __shared__ float b2s;
    const int tid = threadIdx.x;
    const int isbf = flagp[0];
    for (int i = tid; i < 34 * HN; i += 256) W1s[i] = ldf(W1, i, isbf);
    if (tid < HN) {
        b1s[tid] = ldf(b1, tid, isbf);
        W2s[tid] = ldf(W2, tid, isbf);
    }
    if (tid == 0) b2s = ldf(b2, 0, isbf);
    __syncthreads();

    const int lane = tid & 31;
    const int v = blockIdx.x * 8 + (tid >> 5);
    if (v >= N) return;

    float rep = rep_in[(size_t)v * HN + lane];
    float ml  = out0[v];
    float den = denarr[v];
    float zh  = outz[v];
    float am  = funmap(amax_u[0]);
    float term = (1e-8f / den) * exp2f(am - ml);   // log2-domain stabilizer
    float z = zh / (1.0f + term);
    float tv = ldf(t, v, isbf);

    float acc = b1s[lane] + tv * W1s[32 * HN + lane] + z * W1s[33 * HN + lane];
    #pragma unroll
    for (int k = 0; k < HN; ++k)
        acc += __shfl(rep, k, 32) * W1s[k * HN + lane];
    float f1 = fmaxf(acc, 0.f);
    float o = f1 * W2s[lane];
    #pragma unroll
    for (int m = 16; m; m >>= 1) o += __shfl_xor(o, m, 32);

    if (lane == 0) {
        out0[v] = o + b2s;
        outz[v] = z;
    }
}

extern "C" void kernel_launch(void* const* d_in, const int* in_sizes, int n_in,
                              void* d_out, int out_size, void* d_ws, size_t ws_size,
                              hipStream_t stream)
{
    const int N = out_size / 34;   // out[N] + rep[N*32] + z[N]
    const int E = in_sizes[2];

    const void* x    = d_in[0];
    const void* t    = d_in[1];
    const int* row   = (const int*)d_in[2];
    const int* col   = (const int*)d_in[3];
    const void* Wemb = d_in[4];
    const void* bemb = d_in[5];
    const void* Wgcn = d_in[6];
    const void* bgcn = d_in[7];
    const void* W1   = d_in[8];
    const void* b1   = d_in[9];
    const void* W2   = d_in[10];
    const void* b2   = d_in[11];

    const int B   = (N + 255) >> 8;         // coarse buckets (<=512 for N<=131072)
    const int NB1 = (E + CH1 - 1) / CH1;    // phase1/bhist blocks

    // ws: h | hwbuf(bucketed->packed) | csr_src | rowptr | den
    //     | bucket_cnt+amax_u (one memset) | bucket_base | bucket_cursor | flag
    char* wsb = (char*)d_ws;
    size_t off = 0;
    float* h        = (float*)(wsb + off); off += (size_t)N * HN * 4;
    size_t hwbytes  = (size_t)N * HN * 4;  // == N*128B packed line region
    if ((size_t)E * 4 > hwbytes) hwbytes = (size_t)E * 4;
    char*  hwreg    = wsb + off;           off += hwbytes;
    int*   csr_src  = (int*)(wsb + off);   off += (size_t)E * 4;
    int*   rowptr   = (int*)(wsb + off);   off += (size_t)(N + 1) * 4;
    float* den      = (float*)(wsb + off); off += (size_t)N * 4;
    int*   bucket_cnt    = (int*)(wsb + off); off += (size_t)B * 4;
    unsigned int* amax_u = (unsigned int*)(wsb + off); off += 4;
    int*   bucket_base   = (int*)(wsb + off); off += (size_t)(B + 1) * 4;
    int*   bucket_cursor = (int*)(wsb + off); off += (size_t)B * 4;
    int*   flag     = (int*)(wsb + off);   off += 4;

    int*   bucketed = (int*)hwreg;         // phase 1..2
    uint4* packed   = (uint4*)hwreg;       // after phase2: N x 128B fp16 lines
    // blkhist parks in the csr_src region (dead until phase2 overwrites it).
    int*   blkhist  = csr_src;

    // zero bucket_cnt AND amax_u (adjacent) in one memset
    hipMemsetAsync(bucket_cnt, 0, (size_t)(B + 1) * 4, stream);

    bhist_kernel<<<NB1, 512, 0, stream>>>(col, bucket_cnt, E, B, blkhist,
                                          (const unsigned int*)x, flag);
    embed1_kernel<<<(N + 31) / 32, 256, 0, stream>>>(x, Wemb, bemb, flag, h, N);
    bscan_kernel<<<1, 512, 0, stream>>>(bucket_cnt, bucket_base,
                                        bucket_cursor, rowptr, B, N, E);
    phase1_kernel<<<NB1, 512, 0, stream>>>(row, col, blkhist, bucket_cursor,
                                           bucketed, E, B);
    phase2_kernel<<<B, 256, 0, stream>>>(bucketed, bucket_base, rowptr,
                                         csr_src, N);
    embed2_kernel<<<(N + 31) / 32, 256, 0, stream>>>(h, Wgcn, rowptr, flag,
                                                     packed, N);

    float* outp = (float*)d_out;
    float* out0 = outp;
    float* outr = outp + N;
    float* outz = outp + (size_t)N * 33;

    passB_kernel<<<(N + 7) / 8, 256, 0, stream>>>(
        h, packed, csr_src, rowptr, t, bgcn, flag, outr, outz, out0, den, N);
    amax1_kernel<<<256, 256, 0, stream>>>(out0, amax_u, N);
    final_kernel<<<(N + 7) / 8, 256, 0, stream>>>(
        outr, t, flag, amax_u, den, W1, b1, W2, b2, out0, outz, N);
}

// Round 14
// 329.326 us; speedup vs baseline: 1.1973x; 1.0018x over previous
//
#include <hip/hip_runtime.h>
#include <hip/hip_bf16.h>
#include <hip/hip_fp16.h>

static constexpr int HN = 32;     // Hemb == Hgcn == 32
static constexpr int NIN = 128;
static constexpr int CH1 = 8192;  // edges per phase-1 block
static constexpr int CAP2 = 12288; // LDS stage capacity (ints) in phase 2
// sqrt(log2(e)): folded into packed fp16 h so the score dot is in exp2 domain.
static constexpr float SQRT_LOG2E = 1.2011224087864498f;

typedef _Float16 h2v __attribute__((ext_vector_type(2)));
typedef _Float16 f16x8 __attribute__((ext_vector_type(8)));
typedef float f32x4 __attribute__((ext_vector_type(4)));

__device__ __forceinline__ float bf2f(unsigned short u) {
    union { unsigned int i; float f; } v;
    v.i = ((unsigned int)u) << 16;
    return v.f;
}
__device__ __forceinline__ float ldf(const void* p, size_t i, int isbf) {
    return isbf ? bf2f(((const unsigned short*)p)[i]) : ((const float*)p)[i];
}
__device__ __forceinline__ unsigned int pack2h(float a, float b) {
    unsigned short ua = __half_as_ushort(__float2half_rn(a));
    unsigned short ub = __half_as_ushort(__float2half_rn(b));
    return (unsigned int)ua | ((unsigned int)ub << 16);
}
__device__ __forceinline__ float2 up2(unsigned int u) {
    __half2 h2;
    *reinterpret_cast<unsigned int*>(&h2) = u;
    return __half22float2(h2);
}
__device__ __forceinline__ float2 upbf2(unsigned int u) {
    float2 r;
    r.x = bf2f((unsigned short)(u & 0xFFFFu));
    r.y = bf2f((unsigned short)(u >> 16));
    return r;
}
// packed-fp16 2-way dot-accumulate (v_dot2_f32_f16), f32 accumulator.
__device__ __forceinline__ float fd2(unsigned int a, unsigned int b, float c) {
#if __has_builtin(__builtin_amdgcn_fdot2)
    return __builtin_amdgcn_fdot2(__builtin_bit_cast(h2v, a),
                                  __builtin_bit_cast(h2v, b), c, false);
#else
    float2 fa = up2(a), fb = up2(b);
    return c + fa.x * fb.x + fa.y * fb.y;
#endif
}
// order-preserving float->uint map for atomicMax-based global max
__device__ __forceinline__ unsigned int fmap(float f) {
    unsigned int u = __float_as_uint(f);
    return (f >= 0.f) ? (u | 0x80000000u) : ~u;
}
__device__ __forceinline__ float funmap(unsigned int u) {
    return (u & 0x80000000u) ? __uint_as_float(u & 0x7FFFFFFFu)
                             : __uint_as_float(~u);
}

// K1: h = relu(x @ Wemb + bemb) -> fp32, via MFMA (v_mfma_f32_16x16x32_f16).
// Old per-lane dot2 loop was issue-bound (~46us, 320 LDS reads + 256 VALU
// ops/thread, occupancy pinned ~31% regardless of LDS size). MFMA: per wave
// 12 ds_read_b128 + 8 MFMAs total. 64 nodes/block, 4 waves; wave w owns
// nodes 16w..16w+15 x all 32 features (2 N-tiles).
// Fragment layouts (gfx950): A lane=row(l&15), k=(l>>4)*8+i;
// B lane=col(l&15), k=(l>>4)*8+i; C/D col=l&15, row=(l>>4)*4+reg.
__global__ __launch_bounds__(256) void embed1_kernel(
    const void* __restrict__ x,
    const void* __restrict__ Wemb,
    const void* __restrict__ bemb,
    const int* __restrict__ flagp,
    float* __restrict__ h, int N)
{
    __shared__ _Float16 xs[64][136];   // fp16 X tile, pad->2-way conflicts
    __shared__ _Float16 Wt[32][136];   // fp16 W TRANSPOSED [f][k]
    __shared__ float be[HN];
    const int tid = threadIdx.x;
    const int isbf = flagp[0];
    const int n0 = blockIdx.x * 64;

    // stage W transposed (once per block; 4096 scalar writes)
    for (int i = tid; i < NIN * HN; i += 256) {
        int k = i >> 5, f = i & 31;
        Wt[f][k] = (_Float16)__float2half_rn(ldf(Wemb, i, isbf));
    }
    if (tid < HN) be[tid] = ldf(bemb, tid, isbf);

    // stage X tile as fp16 pairs (coalesced 8B global reads)
    if (isbf) {
        const unsigned int* xw = (const unsigned int*)x;   // bf16 pairs
        for (int p = tid; p < 64 * 64; p += 256) {
            int n = p >> 6, kk = p & 63;
            int nn = n0 + n;
            unsigned int u = (nn < N) ? xw[(size_t)nn * 64 + kk] : 0u;
            float2 v = upbf2(u);
            *(unsigned int*)&xs[n][2 * kk] = pack2h(v.x, v.y);
        }
    } else {
        const float2* x2 = (const float2*)x;
        for (int p = tid; p < 64 * 64; p += 256) {
            int n = p >> 6, kk = p & 63;
            int nn = n0 + n;
            float2 v;
            if (nn < N) v = x2[(size_t)nn * 64 + kk];
            else { v.x = 0.f; v.y = 0.f; }
            *(unsigned int*)&xs[n][2 * kk] = pack2h(v.x, v.y);
        }
    }
    __syncthreads();

    const int l = tid & 63;           // lane within wave
    const int w = tid >> 6;           // wave id 0..3 -> nodes 16w..16w+15
    const int row = l & 15;
    const int q = l >> 4;             // k-subgroup 0..3

    f32x4 acc0 = {0.f, 0.f, 0.f, 0.f};
    f32x4 acc1 = {0.f, 0.f, 0.f, 0.f};
    #pragma unroll
    for (int ks = 0; ks < 4; ++ks) {
        int koff = ks * 32 + q * 8;
        f16x8 af = *(const f16x8*)&xs[w * 16 + row][koff];
        f16x8 bf0 = *(const f16x8*)&Wt[row][koff];        // cols 0..15
        f16x8 bf1 = *(const f16x8*)&Wt[row + 16][koff];   // cols 16..31
        acc0 = __builtin_amdgcn_mfma_f32_16x16x32_f16(af, bf0, acc0, 0, 0, 0);
        acc1 = __builtin_amdgcn_mfma_f32_16x16x32_f16(af, bf1, acc1, 0, 0, 0);
    }

    // C/D: col = l&15, row = (l>>4)*4 + reg
    const int c0 = row;               // (l&15)
    #pragma unroll
    for (int reg = 0; reg < 4; ++reg) {
        int r = q * 4 + reg;
        int node = n0 + w * 16 + r;
        if (node < N) {
            h[(size_t)node * HN + c0]      = fmaxf(acc0[reg] + be[c0], 0.f);
            h[(size_t)node * HN + c0 + 16] = fmaxf(acc1[reg] + be[c0 + 16], 0.f);
        }
    }
}

// K2: coarse bucket histogram (bucket = col>>8), LDS-aggregated; stores
// per-block histogram to blkhist for phase1 reuse. Block 0 lanes 0-63 run
// the bf16-vs-fp32 input sniff.
__global__ __launch_bounds__(512) void bhist_kernel(
    const int* __restrict__ col, int* __restrict__ bucket_cnt, int E, int B,
    int* __restrict__ blkhist,
    const unsigned int* __restrict__ xw, int* __restrict__ flag)
{
    __shared__ int hist[512];
    const int t = threadIdx.x;
    const int e0 = blockIdx.x * CH1;
    for (int i = t; i < B; i += 512) hist[i] = 0;
    if (blockIdx.x == 0 && t < 64) {
        int hits = 0;
        #pragma unroll
        for (int k = 0; k < 2; ++k) {
            unsigned int w = xw[t + 64 * k];
            float a = bf2f((unsigned short)(w & 0xFFFFu));
            float aa = fabsf(a);
            if (a == 0.0f || (aa >= 0.000244140625f && aa <= 32.0f)) hits++;
        }
        #pragma unroll
        for (int m = 32; m; m >>= 1) hits += __shfl_xor(hits, m, 64);
        if (t == 0) flag[0] = (hits >= 64) ? 1 : 0;
    }
    __syncthreads();
    #pragma unroll
    for (int k = 0; k < CH1 / 512; ++k) {
        int e = e0 + k * 512 + t;
        if (e < E) atomicAdd(&hist[col[e] >> 8], 1);
    }
    __syncthreads();
    for (int i = t; i < B; i += 512) {
        int v = hist[i];
        blkhist[(size_t)blockIdx.x * B + i] = v;
        if (v) atomicAdd(&bucket_cnt[i], v);
    }
}

// K3: exclusive scan of bucket counts (B <= 512); init cursors; rowptr[N]=E.
__global__ __launch_bounds__(512) void bscan_kernel(
    const int* __restrict__ bucket_cnt, int* __restrict__ bucket_base,
    int* __restrict__ bucket_cursor, int* __restrict__ rowptr,
    int B, int N, int E)
{
    __shared__ int sc[512];
    __shared__ int orig[512];
    const int t = threadIdx.x;
    int v0 = (t < B) ? bucket_cnt[t] : 0;
    sc[t] = v0; orig[t] = v0;
    __syncthreads();
    for (int o = 1; o < 512; o <<= 1) {
        int v = (t >= o) ? sc[t - o] : 0;
        __syncthreads();
        sc[t] += v;
        __syncthreads();
    }
    if (t < B) {
        int ex = sc[t] - orig[t];
        bucket_base[t] = ex;
        bucket_cursor[t] = ex;
    }
    if (t == 0) { bucket_base[B] = E; rowptr[N] = E; }
}

// K4 (phase1): bucketize edges with LDS reorder -> semi-coalesced writes of
// packed words (row<<8 | col&255) grouped by bucket. bucket = col>>8.
// Histogram comes precomputed from bhist via blkhist (single col pass here).
__global__ __launch_bounds__(512) void phase1_kernel(
    const int* __restrict__ row, const int* __restrict__ col,
    const int* __restrict__ blkhist,
    int* __restrict__ bucket_cursor, int* __restrict__ bucketed, int E, int B)
{
    __shared__ int hist[512];
    __shared__ int sc[512];
    __shared__ int cnt[512];
    __shared__ int gbase[512];
    __shared__ int word[CH1];
    __shared__ int dst[CH1];
    const int t = threadIdx.x;
    const int e0 = blockIdx.x * CH1;
    const int M = (E - e0 < CH1) ? (E - e0) : CH1;

    for (int i = t; i < B; i += 512) {
        hist[i] = blkhist[(size_t)blockIdx.x * B + i];
        cnt[i] = 0;
    }
    __syncthreads();
    sc[t] = (t < B) ? hist[t] : 0;
    __syncthreads();
    for (int o = 1; o < 512; o <<= 1) {
        int v = (t >= o) ? sc[t - o] : 0;
        __syncthreads();
        sc[t] += v;
        __syncthreads();
    }
    if (t < B && hist[t])
        gbase[t] = atomicAdd(&bucket_cursor[t], hist[t]);
    __syncthreads();
    #pragma unroll
    for (int k = 0; k < CH1 / 512; ++k) {
        int e = e0 + k * 512 + t;
        if (e < E) {
            int c = col[e], r = row[e];
            int b = c >> 8;
            int lr = atomicAdd(&cnt[b], 1);
            int p = sc[b] - hist[b] + lr;     // exclusive scan + rank
            word[p] = (r << 8) | (c & 255);
            dst[p] = gbase[b] + lr;
        }
    }
    __syncthreads();
    for (int i = t; i < M; i += 512)
        bucketed[dst[i]] = word[i];
}

// K5 (phase2): one block per bucket. Pass 1 counts per-node degrees AND
// saves each edge's per-node rank (rank_s, u16); scan -> rowptr; pass 2
// pure-arithmetic placement into LDS stage; coalesced copy-out.
__global__ __launch_bounds__(256) void phase2_kernel(
    const int* __restrict__ bucketed, const int* __restrict__ bucket_base,
    int* __restrict__ rowptr, int* __restrict__ csr_src, int N)
{
    __shared__ int stage[CAP2];
    __shared__ unsigned short rank_s[CAP2];
    __shared__ int cnt[256];
    __shared__ int sc[256];
    __shared__ int loc[256];
    const int t = threadIdx.x, b = blockIdx.x;
    const int node0 = b << 8;
    const int s0 = bucket_base[b], s1 = bucket_base[b + 1];
    const int segsz = s1 - s0;
    cnt[t] = 0;
    __syncthreads();
    for (int i = s0 + t; i < s1; i += 256) {
        int lc = bucketed[i] & 255;
        int r = atomicAdd(&cnt[lc], 1);
        if (i - s0 < CAP2) rank_s[i - s0] = (unsigned short)r;
    }
    __syncthreads();
    int c = cnt[t];
    sc[t] = c;
    __syncthreads();
    for (int o = 1; o < 256; o <<= 1) {
        int v = (t >= o) ? sc[t - o] : 0;
        __syncthreads();
        sc[t] += v;
        __syncthreads();
    }
    int ex = sc[t] - c;                 // local exclusive offset
    loc[t] = ex;
    if (node0 + t < N) rowptr[node0 + t] = s0 + ex;
    cnt[t] = 0;                         // placement cursor (fallback path only)
    __syncthreads();
    if (segsz <= CAP2) {
        for (int i = s0 + t; i < s1; i += 256) {
            int w = bucketed[i];
            stage[loc[w & 255] + rank_s[i - s0]] = w >> 8;
        }
        __syncthreads();
        for (int i = t; i < segsz; i += 256) csr_src[s0 + i] = stage[i];
    } else {
        for (int i = s0 + t; i < s1; i += 256) {
            int w = bucketed[i];
            int lc = w & 255;
            int off = loc[lc] + atomicAdd(&cnt[lc], 1);
            csr_src[s0 + off] = w >> 8;
        }
    }
}

// K8: packed[v] = one 128B line per node: 8 chunks of {h[4j..4j+3] fp16
// (pre-scaled by sqrt(log2e)), hws[4j..4j+3] fp16} with hws = dis*(h@Wgcn).
__global__ __launch_bounds__(256) void embed2_kernel(
    const float* __restrict__ h, const void* __restrict__ Wgcn,
    const int* __restrict__ rowptr, const int* __restrict__ flagp,
    uint4* __restrict__ packed, int N)
{
    __shared__ float Wg[HN * HN];
    __shared__ float hs[32][HN + 1];
    __shared__ float ws[32][HN + 1];
    const int tid = threadIdx.x;
    const int isbf = flagp[0];
    for (int i = tid; i < HN * HN; i += 256) Wg[i] = ldf(Wgcn, i, isbf);
    const int n0 = blockIdx.x * 32;
    for (int i = tid; i < 32 * HN; i += 256) {
        int n = i >> 5, f = i & 31;
        hs[n][f] = (n0 + n < N) ? h[(size_t)(n0 + n) * HN + f] : 0.f;
    }
    __syncthreads();
    const int f = tid & 31, ns = tid >> 5;
    #pragma unroll
    for (int g = 0; g < 4; ++g) {
        int n = ns + 8 * g, v = n0 + n;
        float acc = 0.f;
        #pragma unroll
        for (int k = 0; k < HN; ++k) acc += hs[n][k] * Wg[k * HN + f];
        float dis = (v < N) ? rsqrtf((float)(rowptr[v + 1] - rowptr[v]) + 1.0f) : 0.f;
        ws[n][f] = dis * acc;
    }
    __syncthreads();
    const int n = tid >> 3, jj = tid & 7, v = n0 + n;
    if (v < N) {
        uint4 w;
        w.x = pack2h(hs[n][4 * jj + 0] * SQRT_LOG2E, hs[n][4 * jj + 1] * SQRT_LOG2E);
        w.y = pack2h(hs[n][4 * jj + 2] * SQRT_LOG2E, hs[n][4 * jj + 3] * SQRT_LOG2E);
        w.z = pack2h(ws[n][4 * jj + 0], ws[n][4 * jj + 1]);
        w.w = pack2h(ws[n][4 * jj + 2], ws[n][4 * jj + 3]);
        packed[(size_t)v * 8 + jj] = w;
    }
}

// K9 (passB): fused gather pass, online softmax (exp2 domain), fdot2 scores.
// 4-deep edge unroll. Single dispatch.
__global__ __launch_bounds__(256) void passB_kernel(
    const float* __restrict__ h, const uint4* __restrict__ packed,
    const int* __restrict__ csr_src, const int* __restrict__ rowptr,
    const void* __restrict__ t, const void* __restrict__ bgcn,
    const int* __restrict__ flagp,
    float* __restrict__ outr, float* __restrict__ outz,
    float* __restrict__ out0_ml, float* __restrict__ denout, int N)
{
    const int tid = threadIdx.x;
    const int lane = tid & 31;
    const int sub = lane >> 3;
    const int j = lane & 7;
    const int v = blockIdx.x * 8 + (tid >> 5);
    if (v >= N) return;
    const int isbf = flagp[0];

    const float4* h4 = (const float4*)h;
    float4 hv = h4[(size_t)v * 8 + j];          // fp32 self (rep path)
    uint4 sw = packed[(size_t)v * 8 + j];       // self line: scaled h + hws
    float2 wsv0 = up2(sw.z), wsv1 = up2(sw.w);
    const int s = rowptr[v], e2 = rowptr[v + 1];

    float m = -1e30f, den = 0.f, num = 0.f;     // m in log2 domain
    float ax = 0.f, ay = 0.f, az = 0.f, aw = 0.f;
    int i = s + sub;
    for (; i + 12 < e2; i += 16) {
        int r0 = csr_src[i];
        int r1 = csr_src[i + 4];
        int r2 = csr_src[i + 8];
        int r3 = csr_src[i + 12];
        uint4 w0 = packed[(size_t)r0 * 8 + j];
        uint4 w1 = packed[(size_t)r1 * 8 + j];
        uint4 w2 = packed[(size_t)r2 * 8 + j];
        uint4 w3 = packed[(size_t)r3 * 8 + j];
        float tr0 = ldf(t, r0, isbf);
        float tr1 = ldf(t, r1, isbf);
        float tr2 = ldf(t, r2, isbf);
        float tr3 = ldf(t, r3, isbf);
        float p0 = fd2(w0.x, sw.x, fd2(w0.y, sw.y, 0.f));
        float p1 = fd2(w1.x, sw.x, fd2(w1.y, sw.y, 0.f));
        float p2 = fd2(w2.x, sw.x, fd2(w2.y, sw.y, 0.f));
        float p3 = fd2(w3.x, sw.x, fd2(w3.y, sw.y, 0.f));
        p0 += __shfl_xor(p0, 1, 32);
        p0 += __shfl_xor(p0, 2, 32);
        p0 += __shfl_xor(p0, 4, 32);
        p1 += __shfl_xor(p1, 1, 32);
        p1 += __shfl_xor(p1, 2, 32);
        p1 += __shfl_xor(p1, 4, 32);
        p2 += __shfl_xor(p2, 1, 32);
        p2 += __shfl_xor(p2, 2, 32);
        p2 += __shfl_xor(p2, 4, 32);
        p3 += __shfl_xor(p3, 1, 32);
        p3 += __shfl_xor(p3, 2, 32);
        p3 += __shfl_xor(p3, 4, 32);
        float2 a00 = up2(w0.z), a01 = up2(w0.w);
        float2 a10 = up2(w1.z), a11 = up2(w1.w);
        float2 a20 = up2(w2.z), a21 = up2(w2.w);
        float2 a30 = up2(w3.z), a31 = up2(w3.w);
        ax += (a00.x + a10.x) + (a20.x + a30.x);
        ay += (a00.y + a10.y) + (a20.y + a30.y);
        az += (a01.x + a11.x) + (a21.x + a31.x);
        aw += (a01.y + a11.y) + (a21.y + a31.y);
        float mn = fmaxf(m, fmaxf(fmaxf(p0, p1), fmaxf(p2, p3)));
        float corr = exp2f(m - mn);
        float e0 = exp2f(p0 - mn), e1 = exp2f(p1 - mn);
        float e2x = exp2f(p2 - mn), e3 = exp2f(p3 - mn);
        den = den * corr + (e0 + e1) + (e2x + e3);
        num = num * corr + (e0 * tr0 + e1 * tr1) + (e2x * tr2 + e3 * tr3);
        m = mn;
    }
    for (; i + 4 < e2; i += 8) {
        int r0 = csr_src[i];
        int r1 = csr_src[i + 4];
        uint4 w0 = packed[(size_t)r0 * 8 + j];
        uint4 w1 = packed[(size_t)r1 * 8 + j];
        float tr0 = ldf(t, r0, isbf);
        float tr1 = ldf(t, r1, isbf);
        float p0 = fd2(w0.x, sw.x, fd2(w0.y, sw.y, 0.f));
        float p1 = fd2(w1.x, sw.x, fd2(w1.y, sw.y, 0.f));
        p0 += __shfl_xor(p0, 1, 32);
        p0 += __shfl_xor(p0, 2, 32);
        p0 += __shfl_xor(p0, 4, 32);
        p1 += __shfl_xor(p1, 1, 32);
        p1 += __shfl_xor(p1, 2, 32);
        p1 += __shfl_xor(p1, 4, 32);
        float2 a00 = up2(w0.z), a01 = up2(w0.w);
        float2 a10 = up2(w1.z), a11 = up2(w1.w);
        ax += a00.x + a10.x; ay += a00.y + a10.y;
        az += a01.x + a11.x; aw += a01.y + a11.y;
        float mn = fmaxf(m, fmaxf(p0, p1));
        float corr = exp2f(m - mn);
        float e0 = exp2f(p0 - mn), e1 = exp2f(p1 - mn);
        den = den * corr + e0 + e1;
        num = num * corr + e0 * tr0 + e1 * tr1;
        m = mn;
    }
    if (i < e2) {
        int r0 = csr_src[i];
        uint4 w0 = packed[(size_t)r0 * 8 + j];
        float tr0 = ldf(t, r0, isbf);
        float p0 = fd2(w0.x, sw.x, fd2(w0.y, sw.y, 0.f));
        p0 += __shfl_xor(p0, 1, 32);
        p0 += __shfl_xor(p0, 2, 32);
        p0 += __shfl_xor(p0, 4, 32);
        float2 a00 = up2(w0.z), a01 = up2(w0.w);
        ax += a00.x; ay += a00.y; az += a01.x; aw += a01.y;
        float mn = fmaxf(m, p0);
        float corr = exp2f(m - mn);
        float e0 = exp2f(p0 - mn);
        den = den * corr + e0;
        num = num * corr + e0 * tr0;
        m = mn;
    }
    #pragma unroll
    for (int o = 8; o <= 16; o <<= 1) {
        float mo = __shfl_xor(m, o, 32);
        float dno = __shfl_xor(den, o, 32);
        float nmo = __shfl_xor(num, o, 32);
        float mn = fmaxf(m, mo);
        float ca = exp2f(m - mn), cb = exp2f(mo - mn);
        den = den * ca + dno * cb;
        num = num * ca + nmo * cb;
        m = mn;
        ax += __shfl_xor(ax, o, 32);
        ay += __shfl_xor(ay, o, 32);
        az += __shfl_xor(az, o, 32);
        aw += __shfl_xor(aw, o, 32);
    }

    float dv = rsqrtf((float)(e2 - s) + 1.0f);
    float4 rep;
    rep.x = hv.x + fmaxf(dv * (ax + wsv0.x) + ldf(bgcn, 4 * j + 0, isbf), 0.f);
    rep.y = hv.y + fmaxf(dv * (ay + wsv0.y) + ldf(bgcn, 4 * j + 1, isbf), 0.f);
    rep.z = hv.z + fmaxf(dv * (az + wsv1.x) + ldf(bgcn, 4 * j + 2, isbf), 0.f);
    rep.w = hv.w + fmaxf(dv * (aw + wsv1.y) + ldf(bgcn, 4 * j + 3, isbf), 0.f);
    if (sub == 0)
        ((float4*)outr)[(size_t)v * 8 + j] = rep;
    if (lane == 0) {
        outz[v]    = num / fmaxf(den, 1e-37f);
        out0_ml[v] = m;          // log2 domain
        denout[v]  = den;
    }
}

// K10: global max over per-node local maxes -> single global atomicMax
// (order-preserving uint mapping; amax_u pre-zeroed = -inf).
__global__ __launch_bounds__(256) void amax1_kernel(
    const float* __restrict__ ml, unsigned int* __restrict__ amax_u, int N)
{
    float m = -INFINITY;
    for (int i = blockIdx.x * 256 + threadIdx.x; i < N; i += 256 * 256)
        m = fmaxf(m, ml[i]);
    #pragma unroll
    for (int s = 32; s; s >>= 1) m = fmaxf(m, __shfl_xor(m, s, 64));
    __shared__ float sm[4];
    if ((threadIdx.x & 63) == 0) sm[threadIdx.x >> 6] = m;
    __syncthreads();
    if (threadIdx.x == 0) {
        float bm = fmaxf(fmaxf(sm[0], sm[1]), fmaxf(sm[2], sm[3]));
        atomicMax(amax_u, fmap(bm));
    }
}

// K11: exact epsilon correction (log2 domain) + FF head.
__global__ __launch_bounds__(256) void final_kernel(
    const float* __restrict__ rep_in,
    const void* __restrict__ t, const int* __restrict__ flagp,
    const unsigned int* __restrict__ amax_u, const float* __restrict__ denarr,
    const void* __restrict__ W1, const void* __restrict__ b1,
    const void* __restrict__ W2, const void* __restrict__ b2,
    float* __restrict__ out0, float* __restrict__ outz, int N)
{
    __shared__ float W1s[34 * HN];
    __shared__ float b1s[HN], W2s[HN];
    __shared__ float b2s;
    const int tid = threadIdx.x;
    const int isbf = flagp[0];
    for (int i = tid; i < 34 * HN; i += 256) W1s[i] = ldf(W1, i, isbf);
    if (tid < HN) {
        b1s[tid] = ldf(b1, tid, isbf);
        W2s[tid] = ldf(W2, tid, isbf);
    }
    if (tid == 0) b2s = ldf(b2, 0, isbf);
    __syncthreads();

    const int lane = tid & 31;
    const int v = blockIdx.x * 8 + (tid >> 5);
    if (v >= N) return;

    float rep = rep_in[(size_t)v * HN + lane];
    float ml  = out0[v];
    float den = denarr[v];
    float zh  = outz[v];
    float am  = funmap(amax_u[0]);
    float term = (1e-8f / den) * exp2f(am - ml);   // log2-domain stabilizer
    float z = zh / (1.0f + term);
    float tv = ldf(t, v, isbf);

    float acc = b1s[lane] + tv * W1s[32 * HN + lane] + z * W1s[33 * HN + lane];
    #pragma unroll
    for (int k = 0; k < HN; ++k)
        acc += __shfl(rep, k, 32) * W1s[k * HN + lane];
    float f1 = fmaxf(acc, 0.f);
    float o = f1 * W2s[lane];
    #pragma unroll
    for (int m = 16; m; m >>= 1) o += __shfl_xor(o, m, 32);

    if (lane == 0) {
        out0[v] = o + b2s;
        outz[v] = z;
    }
}

extern "C" void kernel_launch(void* const* d_in, const int* in_sizes, int n_in,
                              void* d_out, int out_size, void* d_ws, size_t ws_size,
                              hipStream_t stream)
{
    const int N = out_size / 34;   // out[N] + rep[N*32] + z[N]
    const int E = in_sizes[2];

    const void* x    = d_in[0];
    const void* t    = d_in[1];
    const int* row   = (const int*)d_in[2];
    const int* col   = (const int*)d_in[3];
    const void* Wemb = d_in[4];
    const void* bemb = d_in[5];
    const void* Wgcn = d_in[6];
    const void* bgcn = d_in[7];
    const void* W1   = d_in[8];
    const void* b1   = d_in[9];
    const void* W2   = d_in[10];
    const void* b2   = d_in[11];

    const int B   = (N + 255) >> 8;         // coarse buckets (<=512 for N<=131072)
    const int NB1 = (E + CH1 - 1) / CH1;    // phase1/bhist blocks

    // ws: h | hwbuf(bucketed->packed) | csr_src | rowptr | den
    //     | bucket_cnt+amax_u (one memset) | bucket_base | bucket_cursor | flag
    char* wsb = (char*)d_ws;
    size_t off = 0;
    float* h        = (float*)(wsb + off); off += (size_t)N * HN * 4;
    size_t hwbytes  = (size_t)N * HN * 4;  // == N*128B packed line region
    if ((size_t)E * 4 > hwbytes) hwbytes = (size_t)E * 4;
    char*  hwreg    = wsb + off;           off += hwbytes;
    int*   csr_src  = (int*)(wsb + off);   off += (size_t)E * 4;
    int*   rowptr   = (int*)(wsb + off);   off += (size_t)(N + 1) * 4;
    float* den      = (float*)(wsb + off); off += (size_t)N * 4;
    int*   bucket_cnt    = (int*)(wsb + off); off += (size_t)B * 4;
    unsigned int* amax_u = (unsigned int*)(wsb + off); off += 4;
    int*   bucket_base   = (int*)(wsb + off); off += (size_t)(B + 1) * 4;
    int*   bucket_cursor = (int*)(wsb + off); off += (size_t)B * 4;
    int*   flag     = (int*)(wsb + off);   off += 4;

    int*   bucketed = (int*)hwreg;         // phase 1..2
    uint4* packed   = (uint4*)hwreg;       // after phase2: N x 128B fp16 lines
    // blkhist parks in the csr_src region (dead until phase2 overwrites it).
    int*   blkhist  = csr_src;

    // zero bucket_cnt AND amax_u (adjacent) in one memset
    hipMemsetAsync(bucket_cnt, 0, (size_t)(B + 1) * 4, stream);

    bhist_kernel<<<NB1, 512, 0, stream>>>(col, bucket_cnt, E, B, blkhist,
                                          (const unsigned int*)x, flag);
    embed1_kernel<<<(N + 63) / 64, 256, 0, stream>>>(x, Wemb, bemb, flag, h, N);
    bscan_kernel<<<1, 512, 0, stream>>>(bucket_cnt, bucket_base,
                                        bucket_cursor, rowptr, B, N, E);
    phase1_kernel<<<NB1, 512, 0, stream>>>(row, col, blkhist, bucket_cursor,
                                           bucketed, E, B);
    phase2_kernel<<<B, 256, 0, stream>>>(bucketed, bucket_base, rowptr,
                                         csr_src, N);
    embed2_kernel<<<(N + 31) / 32, 256, 0, stream>>>(h, Wgcn, rowptr, flag,
                                                     packed, N);

    float* outp = (float*)d_out;
    float* out0 = outp;
    float* outr = outp + N;
    float* outz = outp + (size_t)N * 33;

    passB_kernel<<<(N + 7) / 8, 256, 0, stream>>>(
        h, packed, csr_src, rowptr, t, bgcn, flag, outr, outz, out0, den, N);
    amax1_kernel<<<256, 256, 0, stream>>>(out0, amax_u, N);
    final_kernel<<<(N + 7) / 8, 256, 0, stream>>>(
        outr, t, flag, amax_u, den, W1, b1, W2, b2, out0, outz, N);
}